// Round 1
// baseline (693.408 us; speedup 1.0000x reference)
//
#include <hip/hip_runtime.h>
#include <math.h>

#define NN 4096
#define NN4 (NN/4)
#define CAP 2048   // max nonzeros per row tracked in LDS list (avg ~64, max ~120)

// ---------------- zero A ----------------
__global__ void zeroA_kernel(float4* A4) {
    size_t t = blockIdx.x * (size_t)blockDim.x + threadIdx.x;
    size_t total = (size_t)NN * NN / 4;
    size_t stride = (size_t)gridDim.x * blockDim.x;
    for (size_t p = t; p < total; p += stride)
        A4[p] = make_float4(0.f, 0.f, 0.f, 0.f);
}

// ---------------- scatter edges: A[src][dst] += w ----------------
__global__ void scatter_kernel(const int* __restrict__ idx,
                               const float* __restrict__ w,
                               float* __restrict__ A, int m) {
    int e = blockIdx.x * blockDim.x + threadIdx.x;
    if (e < m) {
        int s = idx[2 * e];
        int d = idx[2 * e + 1];
        atomicAdd(A + (size_t)s * NN + d, w[e]);
    }
}

// ---------------- symmetrize in place: A = A + A^T - diag(diag(A)) ----------------
// one thread per ordered pair (i<j) updates both cells; diagonal untouched.
__global__ void symmetrize_kernel(float* __restrict__ A) {
    size_t t = blockIdx.x * (size_t)blockDim.x + threadIdx.x;
    int i = (int)(t >> 12);
    int j = (int)(t & (NN - 1));
    if (i < j) {
        size_t ij = (size_t)i * NN + j;
        size_t ji = (size_t)j * NN + i;
        float s = A[ij] + A[ji];
        A[ij] = s;
        A[ji] = s;
    }
}

// ---------------- per-row: N_i = row sum, D3_i = diag(A^3)_i ----------------
// diag(A^3)_i = sum_j A_ij * dot(row_i, row_j)   (A symmetric)
__global__ __launch_bounds__(256) void diag3_kernel(const float* __restrict__ A,
                                                    float* __restrict__ Nrow,
                                                    float* __restrict__ D3) {
    __shared__ float4 rowi4[NN4];       // 16 KB: row i
    __shared__ int   nzj[CAP];          // nonzero column indices of row i
    __shared__ float nzv[CAP];          // their values
    __shared__ int   cnt;
    __shared__ float red[4];

    const int tid = threadIdx.x;
    const int i = blockIdx.x;
    const float4* Ai4 = (const float4*)(A + (size_t)i * NN);

    if (tid == 0) cnt = 0;
    __syncthreads();

    float nsum = 0.f;
    for (int k4 = tid; k4 < NN4; k4 += 256) {
        float4 v = Ai4[k4];
        rowi4[k4] = v;
        nsum += v.x + v.y + v.z + v.w;
        if (v.x != 0.f) { int p = atomicAdd(&cnt, 1); if (p < CAP) { nzj[p] = 4*k4+0; nzv[p] = v.x; } }
        if (v.y != 0.f) { int p = atomicAdd(&cnt, 1); if (p < CAP) { nzj[p] = 4*k4+1; nzv[p] = v.y; } }
        if (v.z != 0.f) { int p = atomicAdd(&cnt, 1); if (p < CAP) { nzj[p] = 4*k4+2; nzv[p] = v.z; } }
        if (v.w != 0.f) { int p = atomicAdd(&cnt, 1); if (p < CAP) { nzj[p] = 4*k4+3; nzv[p] = v.w; } }
    }
    __syncthreads();

    // N_i reduction
    {
        float v = nsum;
        for (int o = 32; o; o >>= 1) v += __shfl_down(v, o);
        int lane = tid & 63, wv = tid >> 6;
        if (lane == 0) red[wv] = v;
        __syncthreads();
        if (tid == 0) Nrow[i] = red[0] + red[1] + red[2] + red[3];
    }

    float acc = 0.f;
    if (cnt <= CAP) {
        // sparse path: loop over nonzero j of row i
        int m = cnt;
        for (int p = 0; p < m; ++p) {
            int j = nzj[p];
            float aij = nzv[p];
            const float4* Aj4 = (const float4*)(A + (size_t)j * NN);
            float dot = 0.f;
            for (int k4 = tid; k4 < NN4; k4 += 256) {
                float4 a = rowi4[k4];
                float4 b = Aj4[k4];
                dot += a.x * b.x + a.y * b.y + a.z * b.z + a.w * b.w;
            }
            acc += aij * dot;
        }
    } else {
        // dense fallback (cannot trigger at these densities, kept for safety)
        for (int j = 0; j < NN; ++j) {
            float4 q = rowi4[j >> 2];
            float aij = (j & 3) == 0 ? q.x : (j & 3) == 1 ? q.y : (j & 3) == 2 ? q.z : q.w;
            if (aij == 0.f) continue;
            const float4* Aj4 = (const float4*)(A + (size_t)j * NN);
            float dot = 0.f;
            for (int k4 = tid; k4 < NN4; k4 += 256) {
                float4 a = rowi4[k4];
                float4 b = Aj4[k4];
                dot += a.x * b.x + a.y * b.y + a.z * b.z + a.w * b.w;
            }
            acc += aij * dot;
        }
    }

    // D3_i reduction
    {
        __syncthreads();
        float v = acc;
        for (int o = 32; o; o >>= 1) v += __shfl_down(v, o);
        int lane = tid & 63, wv = tid >> 6;
        if (lane == 0) red[wv] = v;
        __syncthreads();
        if (tid == 0) D3[i] = red[0] + red[1] + red[2] + red[3];
    }
}

// ---------------- OLS (normal equations, fp64) + residual sum ----------------
__global__ void stats_kernel(const float* __restrict__ Nrow,
                             const float* __restrict__ D3,
                             const int* __restrict__ lst, int nl,
                             float* __restrict__ out) {
    const int tid = threadIdx.x;
    __shared__ double sh[16];
    __shared__ double wb[2];

    double s1 = 0, s2 = 0, t0 = 0, t1 = 0;
    for (int i = tid; i < NN; i += 256) {
        double Nv = (double)Nrow[i];
        double Ev = Nv + 0.5 * (double)D3[i];
        double ln = log(Nv + 1e-20);
        double le = log(Ev + 1e-20);
        s1 += ln; s2 += ln * ln; t0 += le; t1 += ln * le;
    }
    for (int o = 32; o; o >>= 1) {
        s1 += __shfl_down(s1, o);
        s2 += __shfl_down(s2, o);
        t0 += __shfl_down(t0, o);
        t1 += __shfl_down(t1, o);
    }
    int lane = tid & 63, wv = tid >> 6;
    if (lane == 0) { sh[wv] = s1; sh[4 + wv] = s2; sh[8 + wv] = t0; sh[12 + wv] = t1; }
    __syncthreads();
    if (tid == 0) {
        double S1 = 0, S2 = 0, T0 = 0, T1 = 0;
        for (int k = 0; k < 4; ++k) { S1 += sh[k]; S2 += sh[4+k]; T0 += sh[8+k]; T1 += sh[12+k]; }
        double n = (double)NN;
        double det = n * S2 - S1 * S1;
        double w = (n * T1 - S1 * T0) / det;
        double b = (S2 * T0 - S1 * T1) / det;
        wb[0] = w; wb[1] = b;
    }
    __syncthreads();
    double w = wb[0], b = wb[1];
    double eb = exp(b);
    double acc = 0;
    for (int p = tid; p < nl; p += 256) {
        int i = lst[p];
        double Nv = (double)Nrow[i];
        double Ev = Nv + 0.5 * (double)D3[i];
        double r = eb * pow(Nv, w) - Ev;
        acc += r * r;
    }
    for (int o = 32; o; o >>= 1) acc += __shfl_down(acc, o);
    __syncthreads();
    if (lane == 0) sh[wv] = acc;
    __syncthreads();
    if (tid == 0) out[0] = (float)(sh[0] + sh[1] + sh[2] + sh[3]);
}

extern "C" void kernel_launch(void* const* d_in, const int* in_sizes, int n_in,
                              void* d_out, int out_size, void* d_ws, size_t ws_size,
                              hipStream_t stream) {
    const int*   tri_idx = (const int*)d_in[0];
    const float* tri_w   = (const float*)d_in[1];
    const int*   lst     = (const int*)d_in[2];
    const int m  = in_sizes[1];          // number of edges
    const int nl = in_sizes[2];          // number of targets

    float* A    = (float*)d_ws;                       // 4096*4096 f32 = 64 MiB
    float* Nrow = A + (size_t)NN * NN;                // 4096 f32
    float* D3   = Nrow + NN;                          // 4096 f32
    float* out  = (float*)d_out;

    zeroA_kernel<<<1024, 256, 0, stream>>>((float4*)A);
    scatter_kernel<<<(m + 255) / 256, 256, 0, stream>>>(tri_idx, tri_w, A, m);
    symmetrize_kernel<<<(NN * NN) / 256, 256, 0, stream>>>(A);
    diag3_kernel<<<NN, 256, 0, stream>>>(A, Nrow, D3);
    stats_kernel<<<1, 256, 0, stream>>>(Nrow, D3, lst, nl, out);
}

// Round 2
// 86.591 us; speedup vs baseline: 8.0079x; 8.0079x over previous
//
#include <hip/hip_runtime.h>
#include <math.h>

#define NN 4096
#define NN4 (NN/4)
#define CAP 256    // max nonzeros per row in CSR (Poisson mean ~64, max ~120)

// ---------------- zero A ----------------
__global__ void zeroA_kernel(float4* A4) {
    size_t t = blockIdx.x * (size_t)blockDim.x + threadIdx.x;
    size_t total = (size_t)NN * NN / 4;
    size_t stride = (size_t)gridDim.x * blockDim.x;
    for (size_t p = t; p < total; p += stride)
        A4[p] = make_float4(0.f, 0.f, 0.f, 0.f);
}

// ---------------- scatter edges, symmetrized: A[s][d]+=w and A[d][s]+=w (once if s==d) ----
// Reference: A = scatter(src,dst,w); A = A + A^T - diag(diag(A))
// => off-diag gets both directions, diagonal gets the scattered value once.
__global__ void scatter_kernel(const int* __restrict__ idx,
                               const float* __restrict__ w,
                               float* __restrict__ A, int m) {
    int e = blockIdx.x * blockDim.x + threadIdx.x;
    if (e < m) {
        int s = idx[2 * e];
        int d = idx[2 * e + 1];
        float wv = w[e];
        atomicAdd(A + (size_t)s * NN + d, wv);
        if (s != d) atomicAdd(A + (size_t)d * NN + s, wv);
    }
}

// ---------------- build CSR + row sums from dense A ----------------
__global__ __launch_bounds__(256) void buildcsr_kernel(const float* __restrict__ A,
                                                       int* __restrict__ nnz,
                                                       int* __restrict__ cols,
                                                       float* __restrict__ vals,
                                                       float* __restrict__ Nrow) {
    __shared__ int   lcol[CAP];
    __shared__ float lval[CAP];
    __shared__ int   cnt;
    __shared__ float red[4];

    const int tid = threadIdx.x;
    const int i = blockIdx.x;
    const float4* Ai4 = (const float4*)(A + (size_t)i * NN);

    if (tid == 0) cnt = 0;
    __syncthreads();

    float nsum = 0.f;
    for (int k4 = tid; k4 < NN4; k4 += 256) {
        float4 v = Ai4[k4];
        nsum += v.x + v.y + v.z + v.w;
        if (v.x != 0.f) { int p = atomicAdd(&cnt, 1); if (p < CAP) { lcol[p] = 4*k4+0; lval[p] = v.x; } }
        if (v.y != 0.f) { int p = atomicAdd(&cnt, 1); if (p < CAP) { lcol[p] = 4*k4+1; lval[p] = v.y; } }
        if (v.z != 0.f) { int p = atomicAdd(&cnt, 1); if (p < CAP) { lcol[p] = 4*k4+2; lval[p] = v.z; } }
        if (v.w != 0.f) { int p = atomicAdd(&cnt, 1); if (p < CAP) { lcol[p] = 4*k4+3; lval[p] = v.w; } }
    }
    __syncthreads();

    // N_i reduction
    float v = nsum;
    for (int o = 32; o; o >>= 1) v += __shfl_down(v, o);
    int lane = tid & 63, wv = tid >> 6;
    if (lane == 0) red[wv] = v;
    __syncthreads();
    if (tid == 0) Nrow[i] = red[0] + red[1] + red[2] + red[3];

    int mm = cnt < CAP ? cnt : CAP;
    if (tid == 0) nnz[i] = mm;
    for (int p = tid; p < mm; p += 256) {
        cols[(size_t)i * CAP + p] = lcol[p];
        vals[(size_t)i * CAP + p] = lval[p];
    }
}

// ---------------- diag(A^3)_i via CSR: sum_{j in N(i)} A_ij * sum_{k in N(j)} A_jk * A_ik ----
__global__ __launch_bounds__(256) void diag3_kernel(const int* __restrict__ nnz,
                                                    const int* __restrict__ cols,
                                                    const float* __restrict__ vals,
                                                    float* __restrict__ D3) {
    __shared__ float lrow[NN];       // 16 KB dense image of row i (A_ik lookup)
    __shared__ int   lcol[CAP];
    __shared__ float lval[CAP];
    __shared__ float red[4];

    const int tid = threadIdx.x;
    const int i = blockIdx.x;

    float4* l4 = (float4*)lrow;
    for (int k = tid; k < NN4; k += 256) l4[k] = make_float4(0.f, 0.f, 0.f, 0.f);
    __syncthreads();

    const int mi = nnz[i];
    for (int p = tid; p < mi; p += 256) {
        int c = cols[(size_t)i * CAP + p];
        float vv = vals[(size_t)i * CAP + p];
        lcol[p] = c;
        lval[p] = vv;
        lrow[c] = vv;
    }
    __syncthreads();

    float acc = 0.f;
    const int warp = tid >> 6, lane = tid & 63;
    for (int p = warp; p < mi; p += 4) {
        int j = lcol[p];
        float aij = lval[p];
        int mj = nnz[j];
        const int*   cj = cols + (size_t)j * CAP;
        const float* vj = vals + (size_t)j * CAP;
        float d = 0.f;
        for (int q = lane; q < mj; q += 64)
            d += vj[q] * lrow[cj[q]];
        acc += aij * d;
    }

    float v = acc;
    for (int o = 32; o; o >>= 1) v += __shfl_down(v, o);
    if (lane == 0) red[warp] = v;
    __syncthreads();
    if (tid == 0) D3[i] = red[0] + red[1] + red[2] + red[3];
}

// ---------------- OLS (normal equations, fp64) + residual sum ----------------
__global__ void stats_kernel(const float* __restrict__ Nrow,
                             const float* __restrict__ D3,
                             const int* __restrict__ lst, int nl,
                             float* __restrict__ out) {
    const int tid = threadIdx.x;
    __shared__ double sh[16];
    __shared__ double wb[2];

    double s1 = 0, s2 = 0, t0 = 0, t1 = 0;
    for (int i = tid; i < NN; i += 256) {
        double Nv = (double)Nrow[i];
        double Ev = Nv + 0.5 * (double)D3[i];
        double ln = log(Nv + 1e-20);
        double le = log(Ev + 1e-20);
        s1 += ln; s2 += ln * ln; t0 += le; t1 += ln * le;
    }
    for (int o = 32; o; o >>= 1) {
        s1 += __shfl_down(s1, o);
        s2 += __shfl_down(s2, o);
        t0 += __shfl_down(t0, o);
        t1 += __shfl_down(t1, o);
    }
    int lane = tid & 63, wv = tid >> 6;
    if (lane == 0) { sh[wv] = s1; sh[4 + wv] = s2; sh[8 + wv] = t0; sh[12 + wv] = t1; }
    __syncthreads();
    if (tid == 0) {
        double S1 = 0, S2 = 0, T0 = 0, T1 = 0;
        for (int k = 0; k < 4; ++k) { S1 += sh[k]; S2 += sh[4+k]; T0 += sh[8+k]; T1 += sh[12+k]; }
        double n = (double)NN;
        double det = n * S2 - S1 * S1;
        double w = (n * T1 - S1 * T0) / det;
        double b = (S2 * T0 - S1 * T1) / det;
        wb[0] = w; wb[1] = b;
    }
    __syncthreads();
    double w = wb[0], b = wb[1];
    double eb = exp(b);
    double acc = 0;
    for (int p = tid; p < nl; p += 256) {
        int i = lst[p];
        double Nv = (double)Nrow[i];
        double Ev = Nv + 0.5 * (double)D3[i];
        double r = eb * pow(Nv, w) - Ev;
        acc += r * r;
    }
    for (int o = 32; o; o >>= 1) acc += __shfl_down(acc, o);
    __syncthreads();
    if (lane == 0) sh[wv] = acc;
    __syncthreads();
    if (tid == 0) out[0] = (float)(sh[0] + sh[1] + sh[2] + sh[3]);
}

extern "C" void kernel_launch(void* const* d_in, const int* in_sizes, int n_in,
                              void* d_out, int out_size, void* d_ws, size_t ws_size,
                              hipStream_t stream) {
    const int*   tri_idx = (const int*)d_in[0];
    const float* tri_w   = (const float*)d_in[1];
    const int*   lst     = (const int*)d_in[2];
    const int m  = in_sizes[1];          // number of edges
    const int nl = in_sizes[2];          // number of targets

    float* A    = (float*)d_ws;                       // 4096*4096 f32 = 64 MiB
    float* Nrow = A + (size_t)NN * NN;                // 4096 f32
    float* D3   = Nrow + NN;                          // 4096 f32
    int*   nnz  = (int*)(D3 + NN);                    // 4096 i32
    int*   cols = nnz + NN;                           // 4096*CAP i32 = 4 MiB
    float* vals = (float*)(cols + (size_t)NN * CAP);  // 4096*CAP f32 = 4 MiB
    float* out  = (float*)d_out;

    zeroA_kernel<<<2048, 256, 0, stream>>>((float4*)A);
    scatter_kernel<<<(m + 255) / 256, 256, 0, stream>>>(tri_idx, tri_w, A, m);
    buildcsr_kernel<<<NN, 256, 0, stream>>>(A, nnz, cols, vals, Nrow);
    diag3_kernel<<<NN, 256, 0, stream>>>(nnz, cols, vals, D3);
    stats_kernel<<<1, 256, 0, stream>>>(Nrow, D3, lst, nl, out);
}

// Round 3
// 75.565 us; speedup vs baseline: 9.1763x; 1.1459x over previous
//
#include <hip/hip_runtime.h>
#include <math.h>

#define NN 4096
#define NN4 (NN/4)
#define CAP 256    // max raw entries per row (Poisson mean ~64, max ~120)

// ---------------- zero per-row entry counters ----------------
__global__ void zerocnt_kernel(int* __restrict__ cnt) {
    int t = blockIdx.x * blockDim.x + threadIdx.x;
    if (t < NN) cnt[t] = 0;
}

// ---------------- scatter edges directly into fixed-stride adjacency lists ----
// Reference: A = scatter(src,dst,w); A = A + A^T - diag(diag(A))
// => row s gets (d,w), row d gets (s,w) (once if s==d). Duplicates kept raw.
__global__ void scatter_kernel(const int* __restrict__ idx,
                               const float* __restrict__ w,
                               int* __restrict__ cnt,
                               int2* __restrict__ ent, int m) {
    int e = blockIdx.x * blockDim.x + threadIdx.x;
    if (e < m) {
        int s = idx[2 * e];
        int d = idx[2 * e + 1];
        float wv = w[e];
        int2 pk;
        pk.y = __float_as_int(wv);
        int p = atomicAdd(cnt + s, 1);
        if (p < CAP) { pk.x = d; ent[(size_t)s * CAP + p] = pk; }
        if (s != d) {
            int q = atomicAdd(cnt + d, 1);
            if (q < CAP) { pk.x = s; ent[(size_t)d * CAP + q] = pk; }
        }
    }
}

// ---------------- per-row: N_i = sum of entry weights; D3_i = diag(A^3)_i ----
// diag(A^3)_i = sum_{(j,w) in row i} w * sum_{(k,w') in row j} w' * A_ik
// A_ik looked up from a dense LDS image of row i (duplicates merged via LDS atomicAdd).
__global__ __launch_bounds__(256) void diag3_kernel(const int* __restrict__ cnt,
                                                    const int2* __restrict__ ent,
                                                    float* __restrict__ Nrow,
                                                    float* __restrict__ D3) {
    __shared__ float lrow[NN];       // 16 KB dense image of row i
    __shared__ int   lcol[CAP];
    __shared__ float lval[CAP];
    __shared__ float red[8];

    const int tid = threadIdx.x;
    const int i = blockIdx.x;
    const int warp = tid >> 6, lane = tid & 63;

    float4* l4 = (float4*)lrow;
    for (int k = tid; k < NN4; k += 256) l4[k] = make_float4(0.f, 0.f, 0.f, 0.f);
    __syncthreads();

    int mi = cnt[i];
    if (mi > CAP) mi = CAP;
    float nsum = 0.f;
    for (int p = tid; p < mi; p += 256) {
        int2 pk = ent[(size_t)i * CAP + p];
        float vv = __int_as_float(pk.y);
        lcol[p] = pk.x;
        lval[p] = vv;
        nsum += vv;
        atomicAdd(&lrow[pk.x], vv);   // merge duplicate columns (exact int-valued adds)
    }
    // N_i reduction (raw weights sum == row sum)
    for (int o = 32; o; o >>= 1) nsum += __shfl_down(nsum, o);
    if (lane == 0) red[warp] = nsum;
    __syncthreads();
    if (tid == 0) Nrow[i] = red[0] + red[1] + red[2] + red[3];

    float acc = 0.f;
    for (int p = warp; p < mi; p += 4) {
        int j = lcol[p];
        float aij = lval[p];
        int mj = cnt[j];
        if (mj > CAP) mj = CAP;
        const int2* ej = ent + (size_t)j * CAP;
        float d = 0.f;
        for (int q = lane; q < mj; q += 64) {
            int2 pk = ej[q];
            d += __int_as_float(pk.y) * lrow[pk.x];
        }
        acc += aij * d;
    }

    for (int o = 32; o; o >>= 1) acc += __shfl_down(acc, o);
    if (lane == 0) red[4 + warp] = acc;
    __syncthreads();
    if (tid == 0) D3[i] = red[4] + red[5] + red[6] + red[7];
}

// ---------------- OLS (normal equations, fp64) + residual sum ----------------
__global__ void stats_kernel(const float* __restrict__ Nrow,
                             const float* __restrict__ D3,
                             const int* __restrict__ lst, int nl,
                             float* __restrict__ out) {
    const int tid = threadIdx.x;
    __shared__ double sh[16];
    __shared__ double wb[2];

    double s1 = 0, s2 = 0, t0 = 0, t1 = 0;
    for (int i = tid; i < NN; i += 256) {
        double Nv = (double)Nrow[i];
        double Ev = Nv + 0.5 * (double)D3[i];
        double ln = log(Nv + 1e-20);
        double le = log(Ev + 1e-20);
        s1 += ln; s2 += ln * ln; t0 += le; t1 += ln * le;
    }
    for (int o = 32; o; o >>= 1) {
        s1 += __shfl_down(s1, o);
        s2 += __shfl_down(s2, o);
        t0 += __shfl_down(t0, o);
        t1 += __shfl_down(t1, o);
    }
    int lane = tid & 63, wv = tid >> 6;
    if (lane == 0) { sh[wv] = s1; sh[4 + wv] = s2; sh[8 + wv] = t0; sh[12 + wv] = t1; }
    __syncthreads();
    if (tid == 0) {
        double S1 = 0, S2 = 0, T0 = 0, T1 = 0;
        for (int k = 0; k < 4; ++k) { S1 += sh[k]; S2 += sh[4+k]; T0 += sh[8+k]; T1 += sh[12+k]; }
        double n = (double)NN;
        double det = n * S2 - S1 * S1;
        double w = (n * T1 - S1 * T0) / det;
        double b = (S2 * T0 - S1 * T1) / det;
        wb[0] = w; wb[1] = b;
    }
    __syncthreads();
    double w = wb[0], b = wb[1];
    double eb = exp(b);
    double acc = 0;
    for (int p = tid; p < nl; p += 256) {
        int i = lst[p];
        double Nv = (double)Nrow[i];
        double Ev = Nv + 0.5 * (double)D3[i];
        double r = eb * pow(Nv, w) - Ev;
        acc += r * r;
    }
    for (int o = 32; o; o >>= 1) acc += __shfl_down(acc, o);
    __syncthreads();
    if (lane == 0) sh[wv] = acc;
    __syncthreads();
    if (tid == 0) out[0] = (float)(sh[0] + sh[1] + sh[2] + sh[3]);
}

extern "C" void kernel_launch(void* const* d_in, const int* in_sizes, int n_in,
                              void* d_out, int out_size, void* d_ws, size_t ws_size,
                              hipStream_t stream) {
    const int*   tri_idx = (const int*)d_in[0];
    const float* tri_w   = (const float*)d_in[1];
    const int*   lst     = (const int*)d_in[2];
    const int m  = in_sizes[1];          // number of edges
    const int nl = in_sizes[2];          // number of targets

    int*   cnt  = (int*)d_ws;                          // 4096 i32
    int2*  ent  = (int2*)(cnt + NN);                   // 4096*CAP int2 = 8 MiB (col, f32 bits)
    float* Nrow = (float*)(ent + (size_t)NN * CAP);    // 4096 f32
    float* D3   = Nrow + NN;                           // 4096 f32
    float* out  = (float*)d_out;

    zerocnt_kernel<<<NN / 256, 256, 0, stream>>>(cnt);
    scatter_kernel<<<(m + 255) / 256, 256, 0, stream>>>(tri_idx, tri_w, cnt, ent, m);
    diag3_kernel<<<NN, 256, 0, stream>>>(cnt, ent, Nrow, D3);
    stats_kernel<<<1, 256, 0, stream>>>(Nrow, D3, lst, nl, out);
}